// Round 7
// baseline (237.990 us; speedup 1.0000x reference)
//
#include <hip/hip_runtime.h>
#include <math.h>

#define BB 8
#define SS 2048
#define DD 64
#define PAIR_BASE 20000
#define CEPS 1e-8f
#define NROWS (BB * SS)
#define NBND (PAIR_BASE + 1)
#define MAIN_BLOCKS (16 * 16 * BB)           // worst-case GEMM grid (early-exit)
#define POS_BLOCKS (NROWS / 4)               // 4096: 4 waves/block, 1 wave/row
#define TOTAL_BLOCKS (MAIN_BLOCKS + POS_BLOCKS)
#define PREP_BLOCKS (20 + 1 + BB + BB)       // bnd + detect + compact + chains

typedef __bf16 bf16x8 __attribute__((ext_vector_type(8)));
typedef __bf16 bf16x4 __attribute__((ext_vector_type(4)));
typedef float  f32x4  __attribute__((ext_vector_type(4)));

// Workspace (~5 MB of the 256 MB scratch): per-block partials, no same-address
// atomics on the hot path.
struct Ws {
    int byteMode;
    int done;                        // fused-kernel completion counter
    int mc[BB];                      // compacted TF-row count per batch
    int nc[BB];                      // compacted active-col count per batch
    int bnd[NBND];                   // lower_bound(prior, id*20000) per id
    float mpart[MAIN_BLOCKS];
    float ppart[POS_BLOCKS];
    int chead[BB * PAIR_BASE];       // per-batch bucket heads: id -> first col t
    int cnext[NROWS];                // chain links over columns
    __bf16 Uc[(size_t)BB * SS * DD]; // compacted TF rows of u (bf16, zero-pad)
    __bf16 Vc[(size_t)BB * SS * DD]; // compacted active rows of v
};

__device__ __forceinline__ bool read_mask(const void* p, int i, int byteMode) {
    if (byteMode) return ((const unsigned char*)p)[i] != 0;
    return ((const int*)p)[i] != 0;
}

// Kernel 0 (prep, fused; 37 blocks x 1024):
//   blocks 0..19  : prior boundary table bnd[]
//   block  20     : mask-dtype detect -> byteMode; zero done counter
//   blocks 21..28 : per-batch mask scan + compaction gather of u,v -> Uc,Vc
//   blocks 29..36 : per-batch id bucket chains (head/next) for positives
__global__ __launch_bounds__(1024) void prep_kernel(
    const int* __restrict__ ids,
    const int* __restrict__ prior, int M,
    const void* __restrict__ tf_raw,
    const void* __restrict__ act_raw,
    const float* __restrict__ u,
    const float* __restrict__ v,
    Ws* __restrict__ ws)
{
    __shared__ int ssum[1024];
    __shared__ unsigned short cidx[SS];
    __shared__ int stot;
    __shared__ int badl;

    const int blk = blockIdx.x;
    const int tid = threadIdx.x;

    if (blk < 20) {
        // ---- bnd[id] = lower_bound(prior, id*20000) ----
        const int i = blk * 1024 + tid;
        if (i < NBND) {
            const int x = i * PAIR_BASE;            // max 4.0e8 < INT_MAX
            int lo = 0, hi = M;
            while (lo < hi) {
                int mid = (lo + hi) >> 1;
                if (prior[mid] < x) lo = mid + 1; else hi = mid;
            }
            ws->bnd[i] = lo;
        }
    } else if (blk == 20) {
        // ---- mask dtype detect (4 KB; byte-mode false-neg prob 8^-1024) ----
        if (tid == 0) { badl = 0; ws->done = 0; }
        __syncthreads();
        if (((const unsigned int*)tf_raw)[tid] > 1u) atomicOr(&badl, 1);
        __syncthreads();
        if (tid == 0) ws->byteMode = badl;
    } else if (blk < 21 + BB) {
        // ---- per-batch compaction: scan masks, gather bf16 rows, zero-pad ----
        const int b = blk - 21;
        if (tid == 0) badl = 0;
        __syncthreads();
        if (((const unsigned int*)tf_raw)[tid] > 1u) atomicOr(&badl, 1);
        __syncthreads();
        const int bm = badl;

        for (int phase = 0; phase < 2; ++phase) {
            const void* mraw = phase ? act_raw : tf_raw;
            const int e0 = b * SS + 2 * tid;
            const int m0 = read_mask(mraw, e0,     bm) ? 1 : 0;
            const int m1 = read_mask(mraw, e0 + 1, bm) ? 1 : 0;
            ssum[tid] = m0 + m1;
            __syncthreads();
            // Hillis-Steele inclusive scan over 1024 thread-sums
            for (int o = 1; o < 1024; o <<= 1) {
                int val = ssum[tid];
                if (tid >= o) val += ssum[tid - o];
                __syncthreads();
                ssum[tid] = val;
                __syncthreads();
            }
            const int incl = ssum[tid];
            const int excl = incl - m0 - m1;
            if (m0) cidx[excl]      = (unsigned short)(2 * tid);
            if (m1) cidx[excl + m0] = (unsigned short)(2 * tid + 1);
            if (tid == 1023) stot = incl;
            __syncthreads();
            const int total = stot;
            if (tid == 0) { if (phase) ws->nc[b] = total; else ws->mc[b] = total; }
            const int tpad = (total + 127) & ~127;
            __bf16* dst = (phase ? ws->Vc : ws->Uc) + (size_t)b * SS * DD;
            const float* src = (phase ? v : u) + (size_t)b * SS * DD;
            const int r_off = tid >> 4, c = tid & 15;   // 16 threads/row
            for (int r0 = 0; r0 < tpad; r0 += 64) {
                const int r = r0 + r_off;
                if (r < tpad) {
                    bf16x4 hv;
                    if (r < total) {
                        const float4 f = *(const float4*)(src + (size_t)cidx[r] * DD + c * 4);
                        hv = (bf16x4){ (__bf16)f.x, (__bf16)f.y, (__bf16)f.z, (__bf16)f.w };
                    } else {
                        hv = (bf16x4){ (__bf16)0.f, (__bf16)0.f, (__bf16)0.f, (__bf16)0.f };
                    }
                    *(bf16x4*)(dst + (size_t)r * DD + c * 4) = hv;
                }
            }
            __syncthreads();   // before next phase reuses ssum/cidx
        }
    } else {
        // ---- per-batch bucket chains: head[id] -> col t, next[t] -> chain ----
        const int b = blk - (21 + BB);
        int* head = ws->chead + b * PAIR_BASE;
        for (int i = tid; i < PAIR_BASE; i += 1024) head[i] = -1;
        __syncthreads();
        for (int t = tid; t < SS; t += 1024) {
            const int id = ids[b * SS + t];
            const int old = atomicExch(&head[id], t);
            ws->cnext[b * SS + t] = old;
        }
    }
}

// Kernel 1 (fused): GEMM tiles + positive corrections + last-block finalize.
//   blocks [0, MAIN_BLOCKS)              : compacted MFMA tile -> mpart
//   blocks [MAIN_BLOCKS, TOTAL_BLOCKS)   : 4 TF rows each (1 wave/row) -> ppart
// Every block then fences, bumps ws->done; the last block reduces all
// partials + closed-form denominator and writes out[0].
__global__ __launch_bounds__(256) void fused_kernel(
    const int* __restrict__ ids,
    const void* __restrict__ tf_raw,
    const void* __restrict__ act_raw,
    const int* __restrict__ prior,
    const float* __restrict__ u,
    const float* __restrict__ v,
    Ws* __restrict__ ws,
    float* __restrict__ out)
{
    __shared__ __align__(16) __bf16 Ulds[128 * 72];
    __shared__ __align__(16) __bf16 Vlds[128 * 72];
    __shared__ float wsumS[4];
    __shared__ int lastflag;
    __shared__ double sred[256];

    const int bid  = blockIdx.x;
    const int tid  = threadIdx.x;
    const int w    = tid >> 6;
    const int lane = tid & 63;

    float lsum = 0.f;
    float* slot;

    if (bid < MAIN_BLOCKS) {
        // ================= GEMM tile =================
        const int b  = bid >> 8;              // 256 tiles per batch (16x16)
        const int by = (bid >> 4) & 15;
        const int bx = bid & 15;
        const int s0 = by * 128;
        const int t0 = bx * 128;
        slot = &ws->mpart[bid];

        const int mcp = (ws->mc[b] + 127) & ~127;
        const int ncp = (ws->nc[b] + 127) & ~127;
        if (s0 < mcp && t0 < ncp) {
            const __bf16* ub = ws->Uc + (size_t)(b * SS + s0) * DD;
            const __bf16* vb = ws->Vc + (size_t)(b * SS + t0) * DD;
            #pragma unroll
            for (int it = 0; it < 4; ++it) {
                int li = tid + it * 256;      // 128 rows x 8 chunks of 8 bf16
                int r  = li >> 3;
                int c8 = li & 7;
                *(bf16x8*)&Ulds[r * 72 + c8 * 8] = *(const bf16x8*)(ub + r * DD + c8 * 8);
                *(bf16x8*)&Vlds[r * 72 + c8 * 8] = *(const bf16x8*)(vb + r * DD + c8 * 8);
            }
            __syncthreads();

            const int quad = lane >> 4;
            const int l15  = lane & 15;
            const int wm0  = (w >> 1) * 64;
            const int wn0  = (w & 1) * 64;

            f32x4 acc[4][4];
            #pragma unroll
            for (int i = 0; i < 4; ++i)
                #pragma unroll
                for (int j = 0; j < 4; ++j)
                    acc[i][j] = (f32x4){0.f, 0.f, 0.f, 0.f};

            #pragma unroll
            for (int kh = 0; kh < 2; ++kh) {
                const int kcol = kh * 32 + quad * 8;
                bf16x8 af[4], bfr[4];
                #pragma unroll
                for (int ti = 0; ti < 4; ++ti)
                    af[ti] = *(const bf16x8*)&Ulds[(wm0 + ti * 16 + l15) * 72 + kcol];
                #pragma unroll
                for (int tj = 0; tj < 4; ++tj)
                    bfr[tj] = *(const bf16x8*)&Vlds[(wn0 + tj * 16 + l15) * 72 + kcol];
                #pragma unroll
                for (int ti = 0; ti < 4; ++ti)
                    #pragma unroll
                    for (int tj = 0; tj < 4; ++tj)
                        acc[ti][tj] = __builtin_amdgcn_mfma_f32_16x16x32_bf16(
                            af[ti], bfr[tj], acc[ti][tj], 0, 0, 0);
            }

            // Pad rows/cols give dot=0 -> q=1 -> log=0: mask-free epilogue.
            #pragma unroll
            for (int ti = 0; ti < 4; ++ti)
                #pragma unroll
                for (int r = 0; r < 4; ++r)
                    #pragma unroll
                    for (int tj = 0; tj < 4; ++tj) {
                        float q = 1.0f - acc[ti][tj][r];
                        q = fminf(fmaxf(q, CEPS), 1.0f - CEPS);
                        lsum += __logf(q);
                    }
            lsum = -lsum;
        }
    } else {
        // ================= positives: 1 wave per TF row =================
        const int pid = bid - MAIN_BLOCKS;
        const int row = pid * 4 + w;
        const int b   = row >> 11;
        const int bm  = ws->byteMode;
        slot = &ws->ppart[pid];

        if (read_mask(tf_raw, row, bm)) {      // wave-uniform branch
            const int id = ids[row];
            const int lo = ws->bnd[id], hi = ws->bnd[id + 1];
            const int* head = ws->chead + b * PAIR_BASE;
            const int* nxt  = ws->cnext + b * SS;
            const float* urow = u + (size_t)row * DD;
            for (int m = lo + lane; m < hi; m += 64) {
                const int key = prior[m];
                if (m > lo && prior[m - 1] == key) continue;   // dedupe (isin)
                const int tgt = key - id * PAIR_BASE;          // [0, PAIR_BASE)
                for (int t = head[tgt]; t >= 0; t = nxt[t]) {
                    if (read_mask(act_raw, b * SS + t, bm)) {
                        const float* vrow = v + (size_t)(b * SS + t) * DD;
                        float dot = 0.f;
                        #pragma unroll
                        for (int k2 = 0; k2 < DD; k2 += 4) {
                            float4 a = *(const float4*)(urow + k2);
                            float4 c = *(const float4*)(vrow + k2);
                            dot += (float)(__bf16)a.x * (float)(__bf16)c.x;
                            dot += (float)(__bf16)a.y * (float)(__bf16)c.y;
                            dot += (float)(__bf16)a.z * (float)(__bf16)c.z;
                            dot += (float)(__bf16)a.w * (float)(__bf16)c.w;
                        }
                        float p = fminf(fmaxf(dot, CEPS), 1.0f - CEPS);
                        float q = fminf(fmaxf(1.0f - dot, CEPS), 1.0f - CEPS);
                        lsum += __logf(q) - __logf(p);
                    }
                }
            }
        }
    }

    // ---- common tail: block-reduce partial, publish, last block finalizes ----
    #pragma unroll
    for (int o = 32; o > 0; o >>= 1)
        lsum += __shfl_down(lsum, o, 64);
    if (lane == 0) wsumS[w] = lsum;
    __syncthreads();
    if (tid == 0) {
        *slot = wsumS[0] + wsumS[1] + wsumS[2] + wsumS[3];
        __threadfence();                               // publish partial
        const int old = atomicAdd(&ws->done, 1);       // device-scope
        lastflag = (old == TOTAL_BLOCKS - 1) ? 1 : 0;
    }
    __syncthreads();
    if (lastflag) {
        __threadfence();                               // acquire all partials
        double s = 0.0;
        for (int i = tid; i < MAIN_BLOCKS; i += 256) s += (double)ws->mpart[i];
        for (int i = tid; i < POS_BLOCKS;  i += 256) s += (double)ws->ppart[i];
        sred[tid] = s;
        __syncthreads();
        for (int o = 128; o > 0; o >>= 1) {
            if (tid < o) sred[tid] += sred[tid + o];
            __syncthreads();
        }
        if (tid == 0) {
            double denom = 0.0;
            for (int b = 0; b < BB; ++b)
                denom += (double)ws->mc[b] * (double)ws->nc[b];
            out[0] = (float)(sred[0] / (denom + 1e-8));
        }
    }
}

extern "C" void kernel_launch(void* const* d_in, const int* in_sizes, int n_in,
                              void* d_out, int out_size, void* d_ws, size_t ws_size,
                              hipStream_t stream) {
    (void)n_in; (void)out_size; (void)ws_size;
    const int*   ids   = (const int*)d_in[0];
    const void*  tf    = d_in[1];
    const void*  act   = d_in[2];
    const int*   prior = (const int*)d_in[3];
    const int    M     = in_sizes[3];
    const float* u     = (const float*)d_in[4];
    const float* v     = (const float*)d_in[5];
    Ws* ws = (Ws*)d_ws;
    float* out = (float*)d_out;

    prep_kernel<<<PREP_BLOCKS, 1024, 0, stream>>>(ids, prior, M, tf, act, u, v, ws);
    fused_kernel<<<TOTAL_BLOCKS, 256, 0, stream>>>(ids, tf, act, prior, u, v, ws, out);
}

// Round 8
// 133.715 us; speedup vs baseline: 1.7798x; 1.7798x over previous
//
#include <hip/hip_runtime.h>
#include <math.h>

#define BB 8
#define SS 2048
#define DD 64
#define PAIR_BASE 20000
#define CEPS 1e-8f
#define NROWS (BB * SS)
#define NBND (PAIR_BASE + 1)
#define MAIN_BLOCKS (16 * 16 * BB)           // worst-case GEMM grid (early-exit)
#define POS_BLOCKS (NROWS / 4)               // 4096: 4 waves/block, 1 wave/row
#define TOTAL_BLOCKS (MAIN_BLOCKS + POS_BLOCKS)
#define PREP_BLOCKS (20 + 1 + BB + BB)       // bnd + detect + compact + chains

typedef __bf16 bf16x8 __attribute__((ext_vector_type(8)));
typedef __bf16 bf16x4 __attribute__((ext_vector_type(4)));
typedef float  f32x4  __attribute__((ext_vector_type(4)));

// Workspace (~5 MB of scratch): per-block partials, NO cross-block atomics or
// fences on the hot path (R7 lesson: 6144 same-address device atomics +
// __threadfence cost ~25 ns each serialized = 155 us).
struct Ws {
    int byteMode;
    int pad;
    int mc[BB];                      // compacted TF-row count per batch
    int nc[BB];                      // compacted active-col count per batch
    int bnd[NBND];                   // lower_bound(prior, id*20000) per id
    float mpart[MAIN_BLOCKS];
    float ppart[POS_BLOCKS];
    int chead[BB * PAIR_BASE];       // per-batch bucket heads: id -> first col t
    int cnext[NROWS];                // chain links over columns
    __bf16 Uc[(size_t)BB * SS * DD]; // compacted TF rows of u (bf16, zero-pad)
    __bf16 Vc[(size_t)BB * SS * DD]; // compacted active rows of v
};

__device__ __forceinline__ bool read_mask(const void* p, int i, int byteMode) {
    if (byteMode) return ((const unsigned char*)p)[i] != 0;
    return ((const int*)p)[i] != 0;
}

// Kernel 0 (prep, fused; 37 blocks x 1024):
//   blocks 0..19  : prior boundary table bnd[]
//   block  20     : mask-dtype detect -> byteMode
//   blocks 21..28 : per-batch mask scan + compaction gather of u,v -> Uc,Vc
//   blocks 29..36 : per-batch id bucket chains (head/next) for positives
__global__ __launch_bounds__(1024) void prep_kernel(
    const int* __restrict__ ids,
    const int* __restrict__ prior, int M,
    const void* __restrict__ tf_raw,
    const void* __restrict__ act_raw,
    const float* __restrict__ u,
    const float* __restrict__ v,
    Ws* __restrict__ ws)
{
    __shared__ int ssum[1024];
    __shared__ unsigned short cidx[SS];
    __shared__ int stot;
    __shared__ int badl;

    const int blk = blockIdx.x;
    const int tid = threadIdx.x;

    if (blk < 20) {
        // ---- bnd[id] = lower_bound(prior, id*20000) ----
        const int i = blk * 1024 + tid;
        if (i < NBND) {
            const int x = i * PAIR_BASE;            // max 4.0e8 < INT_MAX
            int lo = 0, hi = M;
            while (lo < hi) {
                int mid = (lo + hi) >> 1;
                if (prior[mid] < x) lo = mid + 1; else hi = mid;
            }
            ws->bnd[i] = lo;
        }
    } else if (blk == 20) {
        // ---- mask dtype detect (4 KB; byte-mode false-neg prob 8^-1024) ----
        if (tid == 0) badl = 0;
        __syncthreads();
        if (((const unsigned int*)tf_raw)[tid] > 1u) atomicOr(&badl, 1);
        __syncthreads();
        if (tid == 0) ws->byteMode = badl;
    } else if (blk < 21 + BB) {
        // ---- per-batch compaction: scan masks, gather bf16 rows, zero-pad ----
        const int b = blk - 21;
        if (tid == 0) badl = 0;
        __syncthreads();
        if (((const unsigned int*)tf_raw)[tid] > 1u) atomicOr(&badl, 1);
        __syncthreads();
        const int bm = badl;

        for (int phase = 0; phase < 2; ++phase) {
            const void* mraw = phase ? act_raw : tf_raw;
            const int e0 = b * SS + 2 * tid;
            const int m0 = read_mask(mraw, e0,     bm) ? 1 : 0;
            const int m1 = read_mask(mraw, e0 + 1, bm) ? 1 : 0;
            ssum[tid] = m0 + m1;
            __syncthreads();
            // Hillis-Steele inclusive scan over 1024 thread-sums
            for (int o = 1; o < 1024; o <<= 1) {
                int val = ssum[tid];
                if (tid >= o) val += ssum[tid - o];
                __syncthreads();
                ssum[tid] = val;
                __syncthreads();
            }
            const int incl = ssum[tid];
            const int excl = incl - m0 - m1;
            if (m0) cidx[excl]      = (unsigned short)(2 * tid);
            if (m1) cidx[excl + m0] = (unsigned short)(2 * tid + 1);
            if (tid == 1023) stot = incl;
            __syncthreads();
            const int total = stot;
            if (tid == 0) { if (phase) ws->nc[b] = total; else ws->mc[b] = total; }
            const int tpad = (total + 127) & ~127;
            __bf16* dst = (phase ? ws->Vc : ws->Uc) + (size_t)b * SS * DD;
            const float* src = (phase ? v : u) + (size_t)b * SS * DD;
            const int r_off = tid >> 4, c = tid & 15;   // 16 threads/row
            for (int r0 = 0; r0 < tpad; r0 += 64) {
                const int r = r0 + r_off;
                if (r < tpad) {
                    bf16x4 hv;
                    if (r < total) {
                        const float4 f = *(const float4*)(src + (size_t)cidx[r] * DD + c * 4);
                        hv = (bf16x4){ (__bf16)f.x, (__bf16)f.y, (__bf16)f.z, (__bf16)f.w };
                    } else {
                        hv = (bf16x4){ (__bf16)0.f, (__bf16)0.f, (__bf16)0.f, (__bf16)0.f };
                    }
                    *(bf16x4*)(dst + (size_t)r * DD + c * 4) = hv;
                }
            }
            __syncthreads();   // before next phase reuses ssum/cidx
        }
    } else {
        // ---- per-batch bucket chains: head[id] -> col t, next[t] -> chain ----
        const int b = blk - (21 + BB);
        int* head = ws->chead + b * PAIR_BASE;
        for (int i = tid; i < PAIR_BASE; i += 1024) head[i] = -1;
        __syncthreads();
        for (int t = tid; t < SS; t += 1024) {
            const int id = ids[b * SS + t];
            const int old = atomicExch(&head[id], t);  // block-local table
            ws->cnext[b * SS + t] = old;
        }
    }
}

// Kernel 1 (work, fused): GEMM tiles + positive corrections.  Partials only —
// plain stores; kernel boundary orders them for finalize.
__global__ __launch_bounds__(256) void fused_kernel(
    const int* __restrict__ ids,
    const void* __restrict__ tf_raw,
    const void* __restrict__ act_raw,
    const int* __restrict__ prior,
    const float* __restrict__ u,
    const float* __restrict__ v,
    Ws* __restrict__ ws)
{
    __shared__ __align__(16) __bf16 Ulds[128 * 72];
    __shared__ __align__(16) __bf16 Vlds[128 * 72];
    __shared__ float wsumS[4];

    const int bid  = blockIdx.x;
    const int tid  = threadIdx.x;
    const int w    = tid >> 6;
    const int lane = tid & 63;

    float lsum = 0.f;
    float* slot;

    if (bid < MAIN_BLOCKS) {
        // ================= GEMM tile =================
        const int b  = bid >> 8;              // 256 tiles per batch (16x16)
        const int by = (bid >> 4) & 15;
        const int bx = bid & 15;
        const int s0 = by * 128;
        const int t0 = bx * 128;
        slot = &ws->mpart[bid];

        const int mcp = (ws->mc[b] + 127) & ~127;
        const int ncp = (ws->nc[b] + 127) & ~127;
        if (s0 < mcp && t0 < ncp) {
            const __bf16* ub = ws->Uc + (size_t)(b * SS + s0) * DD;
            const __bf16* vb = ws->Vc + (size_t)(b * SS + t0) * DD;
            #pragma unroll
            for (int it = 0; it < 4; ++it) {
                int li = tid + it * 256;      // 128 rows x 8 chunks of 8 bf16
                int r  = li >> 3;
                int c8 = li & 7;
                *(bf16x8*)&Ulds[r * 72 + c8 * 8] = *(const bf16x8*)(ub + r * DD + c8 * 8);
                *(bf16x8*)&Vlds[r * 72 + c8 * 8] = *(const bf16x8*)(vb + r * DD + c8 * 8);
            }
            __syncthreads();

            const int quad = lane >> 4;
            const int l15  = lane & 15;
            const int wm0  = (w >> 1) * 64;
            const int wn0  = (w & 1) * 64;

            f32x4 acc[4][4];
            #pragma unroll
            for (int i = 0; i < 4; ++i)
                #pragma unroll
                for (int j = 0; j < 4; ++j)
                    acc[i][j] = (f32x4){0.f, 0.f, 0.f, 0.f};

            #pragma unroll
            for (int kh = 0; kh < 2; ++kh) {
                const int kcol = kh * 32 + quad * 8;
                bf16x8 af[4], bfr[4];
                #pragma unroll
                for (int ti = 0; ti < 4; ++ti)
                    af[ti] = *(const bf16x8*)&Ulds[(wm0 + ti * 16 + l15) * 72 + kcol];
                #pragma unroll
                for (int tj = 0; tj < 4; ++tj)
                    bfr[tj] = *(const bf16x8*)&Vlds[(wn0 + tj * 16 + l15) * 72 + kcol];
                #pragma unroll
                for (int ti = 0; ti < 4; ++ti)
                    #pragma unroll
                    for (int tj = 0; tj < 4; ++tj)
                        acc[ti][tj] = __builtin_amdgcn_mfma_f32_16x16x32_bf16(
                            af[ti], bfr[tj], acc[ti][tj], 0, 0, 0);
            }

            // Pad rows/cols give dot=0 -> q=1 -> log=0: mask-free epilogue.
            #pragma unroll
            for (int ti = 0; ti < 4; ++ti)
                #pragma unroll
                for (int r = 0; r < 4; ++r)
                    #pragma unroll
                    for (int tj = 0; tj < 4; ++tj) {
                        float q = 1.0f - acc[ti][tj][r];
                        q = fminf(fmaxf(q, CEPS), 1.0f - CEPS);
                        lsum += __logf(q);
                    }
            lsum = -lsum;
        }
    } else {
        // ================= positives: 1 wave per TF row =================
        const int pid = bid - MAIN_BLOCKS;
        const int row = pid * 4 + w;
        const int b   = row >> 11;
        const int bm  = ws->byteMode;
        slot = &ws->ppart[pid];

        if (read_mask(tf_raw, row, bm)) {      // wave-uniform branch
            const int id = ids[row];
            const int lo = ws->bnd[id], hi = ws->bnd[id + 1];
            const int* head = ws->chead + b * PAIR_BASE;
            const int* nxt  = ws->cnext + b * SS;
            const float* urow = u + (size_t)row * DD;
            for (int m = lo + lane; m < hi; m += 64) {
                const int key = prior[m];
                if (m > lo && prior[m - 1] == key) continue;   // dedupe (isin)
                const int tgt = key - id * PAIR_BASE;          // [0, PAIR_BASE)
                for (int t = head[tgt]; t >= 0; t = nxt[t]) {
                    if (read_mask(act_raw, b * SS + t, bm)) {
                        const float* vrow = v + (size_t)(b * SS + t) * DD;
                        float dot = 0.f;
                        #pragma unroll
                        for (int k2 = 0; k2 < DD; k2 += 4) {
                            float4 a = *(const float4*)(urow + k2);
                            float4 c = *(const float4*)(vrow + k2);
                            dot += (float)(__bf16)a.x * (float)(__bf16)c.x;
                            dot += (float)(__bf16)a.y * (float)(__bf16)c.y;
                            dot += (float)(__bf16)a.z * (float)(__bf16)c.z;
                            dot += (float)(__bf16)a.w * (float)(__bf16)c.w;
                        }
                        float p = fminf(fmaxf(dot, CEPS), 1.0f - CEPS);
                        float q = fminf(fmaxf(1.0f - dot, CEPS), 1.0f - CEPS);
                        lsum += __logf(q) - __logf(p);
                    }
                }
            }
        }
    }

    // ---- tail: block-reduce partial, plain store (no fence, no atomics) ----
    #pragma unroll
    for (int o = 32; o > 0; o >>= 1)
        lsum += __shfl_down(lsum, o, 64);
    if (lane == 0) wsumS[w] = lsum;
    __syncthreads();
    if (tid == 0)
        *slot = wsumS[0] + wsumS[1] + wsumS[2] + wsumS[3];
}

// Kernel 2: finalize — double-sum partials + closed-form denominator.
__global__ __launch_bounds__(256) void finalize_kernel(const Ws* __restrict__ ws,
                                                       float* __restrict__ out) {
    __shared__ double sred[256];
    const int tid = threadIdx.x;
    double s = 0.0;
    for (int i = tid; i < MAIN_BLOCKS; i += 256) s += (double)ws->mpart[i];
    for (int i = tid; i < POS_BLOCKS;  i += 256) s += (double)ws->ppart[i];
    sred[tid] = s;
    __syncthreads();
    for (int o = 128; o > 0; o >>= 1) {
        if (tid < o) sred[tid] += sred[tid + o];
        __syncthreads();
    }
    if (tid == 0) {
        double denom = 0.0;
        for (int b = 0; b < BB; ++b)
            denom += (double)ws->mc[b] * (double)ws->nc[b];
        out[0] = (float)(sred[0] / (denom + 1e-8));
    }
}

extern "C" void kernel_launch(void* const* d_in, const int* in_sizes, int n_in,
                              void* d_out, int out_size, void* d_ws, size_t ws_size,
                              hipStream_t stream) {
    (void)n_in; (void)out_size; (void)ws_size;
    const int*   ids   = (const int*)d_in[0];
    const void*  tf    = d_in[1];
    const void*  act   = d_in[2];
    const int*   prior = (const int*)d_in[3];
    const int    M     = in_sizes[3];
    const float* u     = (const float*)d_in[4];
    const float* v     = (const float*)d_in[5];
    Ws* ws = (Ws*)d_ws;
    float* out = (float*)d_out;

    prep_kernel<<<PREP_BLOCKS, 1024, 0, stream>>>(ids, prior, M, tf, act, u, v, ws);
    fused_kernel<<<TOTAL_BLOCKS, 256, 0, stream>>>(ids, tf, act, prior, u, v, ws);
    finalize_kernel<<<1, 256, 0, stream>>>(ws, out);
}

// Round 9
// 126.510 us; speedup vs baseline: 1.8812x; 1.0570x over previous
//
#include <hip/hip_runtime.h>
#include <math.h>

#define BB 8
#define SS 2048
#define DD 64
#define PAIR_BASE 20000
#define CEPS 1e-8f
#define NROWS (BB * SS)
#define MAIN_BLOCKS (16 * 16 * BB)     // worst-case GEMM grid (early-exit)
#define PPMAX 8192                     // max positives blocks (M <= 262144)
#define PREP_BLOCKS (1 + BB + BB + BB) // detect + compact + row-chains + col-chains

typedef __bf16 bf16x8 __attribute__((ext_vector_type(8)));
typedef __bf16 bf16x4 __attribute__((ext_vector_type(4)));
typedef float  f32x4  __attribute__((ext_vector_type(4)));

// Workspace (~5.6 MB): per-block partials only; no cross-block atomics/fences
// on the hot path (R7 lesson).  Chains replace sorts and binary searches.
struct Ws {
    int byteMode;
    int pad;
    int mc[BB];                       // compacted TF-row count per batch
    int nc[BB];                       // compacted active-col count per batch
    float mpart[MAIN_BLOCKS];
    float ppart[PPMAX];
    int cheadR[BB * PAIR_BASE];       // id -> first TF row s (masked at build)
    int cnextR[NROWS];
    int cheadC[BB * PAIR_BASE];       // id -> first active col t
    int cnextC[NROWS];
    __bf16 Uc[(size_t)BB * SS * DD];  // compacted TF rows of u (bf16, zero-pad)
    __bf16 Vc[(size_t)BB * SS * DD];  // compacted active rows of v
};

__device__ __forceinline__ bool read_mask(const void* p, int i, int byteMode) {
    if (byteMode) return ((const unsigned char*)p)[i] != 0;
    return ((const int*)p)[i] != 0;
}

// Local mask-dtype detect from first 4 KB of tf (valid in both layouts;
// byte-mode false-negative prob 8^-1024).  Needs 1024 threads.
__device__ __forceinline__ int detect_bm(const void* tf_raw, int tid, int* badl) {
    if (tid == 0) *badl = 0;
    __syncthreads();
    if (((const unsigned int*)tf_raw)[tid] > 1u) atomicOr(badl, 1);
    __syncthreads();
    return *badl;
}

// Kernel 0 (prep; 25 blocks x 1024):
//   block  0      : publish byteMode
//   blocks 1..8   : per-batch mask scan (ballot/popc) + gather u,v -> Uc,Vc
//   blocks 9..16  : per-batch TF-row chains   (id -> rows)
//   blocks 17..24 : per-batch active-col chains (id -> cols)
__global__ __launch_bounds__(1024) void prep_kernel(
    const int* __restrict__ ids,
    const void* __restrict__ tf_raw,
    const void* __restrict__ act_raw,
    const float* __restrict__ u,
    const float* __restrict__ v,
    Ws* __restrict__ ws)
{
    __shared__ int badl;
    __shared__ int wsum[16], wbase[16], stot;
    __shared__ unsigned short cidx[SS];

    const int blk = blockIdx.x;
    const int tid = threadIdx.x;
    const int w    = tid >> 6;
    const int lane = tid & 63;

    if (blk == 0) {
        const int bm = detect_bm(tf_raw, tid, &badl);
        if (tid == 0) ws->byteMode = bm;
    } else if (blk <= BB) {
        // ---- per-batch compaction ----
        const int b = blk - 1;
        const int bm = detect_bm(tf_raw, tid, &badl);
        const unsigned long long below = ((unsigned long long)1 << lane) - 1;

        for (int phase = 0; phase < 2; ++phase) {
            const void* mraw = phase ? act_raw : tf_raw;
            const int e0 = b * SS + 2 * tid;
            const int m0 = read_mask(mraw, e0,     bm) ? 1 : 0;
            const int m1 = read_mask(mraw, e0 + 1, bm) ? 1 : 0;
            const unsigned long long k0 = __ballot(m0 != 0);
            const unsigned long long k1 = __ballot(m1 != 0);
            const int exclw = __popcll(k0 & below) + __popcll(k1 & below);
            if (lane == 0) wsum[w] = __popcll(k0) + __popcll(k1);
            __syncthreads();
            if (tid == 0) {
                int run = 0;
                #pragma unroll
                for (int k = 0; k < 16; ++k) { wbase[k] = run; run += wsum[k]; }
                stot = run;
            }
            __syncthreads();
            const int excl = wbase[w] + exclw;
            if (m0) cidx[excl]      = (unsigned short)(2 * tid);
            if (m1) cidx[excl + m0] = (unsigned short)(2 * tid + 1);
            __syncthreads();
            const int total = stot;
            if (tid == 0) { if (phase) ws->nc[b] = total; else ws->mc[b] = total; }
            const int tpad = (total + 127) & ~127;
            __bf16* dst = (phase ? ws->Vc : ws->Uc) + (size_t)b * SS * DD;
            const float* src = (phase ? v : u) + (size_t)b * SS * DD;
            const int r_off = tid >> 4, c = tid & 15;   // 16 threads/row
            for (int r0 = 0; r0 < tpad; r0 += 64) {
                const int r = r0 + r_off;
                if (r < tpad) {
                    bf16x4 hv;
                    if (r < total) {
                        const float4 f = *(const float4*)(src + (size_t)cidx[r] * DD + c * 4);
                        hv = (bf16x4){ (__bf16)f.x, (__bf16)f.y, (__bf16)f.z, (__bf16)f.w };
                    } else {
                        hv = (bf16x4){ (__bf16)0.f, (__bf16)0.f, (__bf16)0.f, (__bf16)0.f };
                    }
                    *(bf16x4*)(dst + (size_t)r * DD + c * 4) = hv;
                }
            }
            __syncthreads();   // before next phase reuses cidx/wsum
        }
    } else if (blk <= 2 * BB) {
        // ---- TF-row chains: headR[id] -> row s (only TF rows inserted) ----
        const int b = blk - (BB + 1);
        const int bm = detect_bm(tf_raw, tid, &badl);
        int* head = ws->cheadR + b * PAIR_BASE;
        for (int i = tid; i < PAIR_BASE; i += 1024) head[i] = -1;
        __syncthreads();
        for (int s = tid; s < SS; s += 1024) {
            if (read_mask(tf_raw, b * SS + s, bm)) {
                const int id = ids[b * SS + s];
                const int old = atomicExch(&head[id], s);
                ws->cnextR[b * SS + s] = old;
            }
        }
    } else {
        // ---- active-col chains: headC[id] -> col t ----
        const int b = blk - (2 * BB + 1);
        const int bm = detect_bm(tf_raw, tid, &badl);
        int* head = ws->cheadC + b * PAIR_BASE;
        for (int i = tid; i < PAIR_BASE; i += 1024) head[i] = -1;
        __syncthreads();
        for (int t = tid; t < SS; t += 1024) {
            if (read_mask(act_raw, b * SS + t, bm)) {
                const int id = ids[b * SS + t];
                const int old = atomicExch(&head[id], t);
                ws->cnextC[b * SS + t] = old;
            }
        }
    }
}

// Kernel 1: compacted MFMA main (unchanged structure; pad rows give log(1)=0).
__global__ __launch_bounds__(256) void prior_loss_main(Ws* __restrict__ ws)
{
    const int b  = blockIdx.z;
    const int s0 = blockIdx.y * 128;
    const int t0 = blockIdx.x * 128;
    const int tid = threadIdx.x;
    const int flat = (blockIdx.z * gridDim.y + blockIdx.y) * gridDim.x + blockIdx.x;

    const int mcp = (ws->mc[b] + 127) & ~127;
    const int ncp = (ws->nc[b] + 127) & ~127;
    if (s0 >= mcp || t0 >= ncp) {
        if (tid == 0) ws->mpart[flat] = 0.f;
        return;
    }

    __shared__ __align__(16) __bf16 Ulds[128 * 72];
    __shared__ __align__(16) __bf16 Vlds[128 * 72];
    __shared__ float wsumS[4];

    const __bf16* ub = ws->Uc + (size_t)(b * SS + s0) * DD;
    const __bf16* vb = ws->Vc + (size_t)(b * SS + t0) * DD;
    #pragma unroll
    for (int it = 0; it < 4; ++it) {
        int li = tid + it * 256;        // 128 rows x 8 chunks of 8 bf16
        int r  = li >> 3;
        int c8 = li & 7;
        *(bf16x8*)&Ulds[r * 72 + c8 * 8] = *(const bf16x8*)(ub + r * DD + c8 * 8);
        *(bf16x8*)&Vlds[r * 72 + c8 * 8] = *(const bf16x8*)(vb + r * DD + c8 * 8);
    }
    __syncthreads();

    const int w    = tid >> 6;
    const int lane = tid & 63;
    const int quad = lane >> 4;
    const int l15  = lane & 15;
    const int wm0  = (w >> 1) * 64;
    const int wn0  = (w & 1) * 64;

    f32x4 acc[4][4];
    #pragma unroll
    for (int i = 0; i < 4; ++i)
        #pragma unroll
        for (int j = 0; j < 4; ++j)
            acc[i][j] = (f32x4){0.f, 0.f, 0.f, 0.f};

    #pragma unroll
    for (int kh = 0; kh < 2; ++kh) {
        const int kcol = kh * 32 + quad * 8;
        bf16x8 af[4], bfr[4];
        #pragma unroll
        for (int ti = 0; ti < 4; ++ti)
            af[ti] = *(const bf16x8*)&Ulds[(wm0 + ti * 16 + l15) * 72 + kcol];
        #pragma unroll
        for (int tj = 0; tj < 4; ++tj)
            bfr[tj] = *(const bf16x8*)&Vlds[(wn0 + tj * 16 + l15) * 72 + kcol];
        #pragma unroll
        for (int ti = 0; ti < 4; ++ti)
            #pragma unroll
            for (int tj = 0; tj < 4; ++tj)
                acc[ti][tj] = __builtin_amdgcn_mfma_f32_16x16x32_bf16(
                    af[ti], bfr[tj], acc[ti][tj], 0, 0, 0);
    }

    float lsum = 0.f;
    #pragma unroll
    for (int ti = 0; ti < 4; ++ti)
        #pragma unroll
        for (int r = 0; r < 4; ++r)
            #pragma unroll
            for (int tj = 0; tj < 4; ++tj) {
                float q = 1.0f - acc[ti][tj][r];
                q = fminf(fmaxf(q, CEPS), 1.0f - CEPS);
                lsum += __logf(q);
            }
    lsum = -lsum;

    #pragma unroll
    for (int o = 32; o > 0; o >>= 1)
        lsum += __shfl_down(lsum, o, 64);
    if (lane == 0) wsumS[w] = lsum;
    __syncthreads();
    if (tid == 0)
        ws->mpart[flat] = wsumS[0] + wsumS[1] + wsumS[2] + wsumS[3];
}

// Kernel 2: positives, prior-entry-driven.  One lane per (batch, prior entry).
// ~95% of lanes exit after one headR load (id absent from TF rows).  No LDS
// tiles, no binary search -> high occupancy, short dependent chains.
__global__ __launch_bounds__(256) void positives_kernel(
    const int* __restrict__ prior, int M,
    const float* __restrict__ u,
    const float* __restrict__ v,
    Ws* __restrict__ ws)
{
    __shared__ float wsumS[4];
    const int tid  = threadIdx.x;
    const int w    = tid >> 6;
    const int lane = tid & 63;
    const int b    = blockIdx.y;
    const int i    = blockIdx.x * 256 + tid;

    float corr = 0.f;
    if (i < M) {
        const int key = prior[i];
        const bool dup = (i > 0) && (prior[i - 1] == key);   // isin dedupe
        if (!dup) {
            const unsigned int uk  = (unsigned int)key;
            const unsigned int src = uk / PAIR_BASE;          // magic-mul
            const unsigned int tgt = uk - src * PAIR_BASE;
            int r = ws->cheadR[b * PAIR_BASE + (int)src];
            if (r >= 0) {
                const int* nxtR = ws->cnextR + b * SS;
                const int* nxtC = ws->cnextC + b * SS;
                const int thead = ws->cheadC[b * PAIR_BASE + (int)tgt];
                for (; r >= 0; r = nxtR[r]) {
                    const float* urow = u + (size_t)(b * SS + r) * DD;
                    for (int t = thead; t >= 0; t = nxtC[t]) {
                        const float* vrow = v + (size_t)(b * SS + t) * DD;
                        float dot = 0.f;
                        #pragma unroll
                        for (int k2 = 0; k2 < DD; k2 += 4) {
                            float4 a = *(const float4*)(urow + k2);
                            float4 c = *(const float4*)(vrow + k2);
                            dot += (float)(__bf16)a.x * (float)(__bf16)c.x;
                            dot += (float)(__bf16)a.y * (float)(__bf16)c.y;
                            dot += (float)(__bf16)a.z * (float)(__bf16)c.z;
                            dot += (float)(__bf16)a.w * (float)(__bf16)c.w;
                        }
                        float p = fminf(fmaxf(dot, CEPS), 1.0f - CEPS);
                        float q = fminf(fmaxf(1.0f - dot, CEPS), 1.0f - CEPS);
                        corr += __logf(q) - __logf(p);
                    }
                }
            }
        }
    }

    #pragma unroll
    for (int o = 32; o > 0; o >>= 1)
        corr += __shfl_down(corr, o, 64);
    if (lane == 0) wsumS[w] = corr;
    __syncthreads();
    if (tid == 0)
        ws->ppart[blockIdx.y * gridDim.x + blockIdx.x] =
            wsumS[0] + wsumS[1] + wsumS[2] + wsumS[3];
}

// Kernel 3: finalize — double-sum partials + closed-form denominator.
__global__ __launch_bounds__(256) void finalize_kernel(const Ws* __restrict__ ws,
                                                       int npp,
                                                       float* __restrict__ out) {
    __shared__ double sred[256];
    const int tid = threadIdx.x;
    double s = 0.0;
    for (int i = tid; i < MAIN_BLOCKS; i += 256) s += (double)ws->mpart[i];
    for (int i = tid; i < npp;         i += 256) s += (double)ws->ppart[i];
    sred[tid] = s;
    __syncthreads();
    for (int o = 128; o > 0; o >>= 1) {
        if (tid < o) sred[tid] += sred[tid + o];
        __syncthreads();
    }
    if (tid == 0) {
        double denom = 0.0;
        for (int b = 0; b < BB; ++b)
            denom += (double)ws->mc[b] * (double)ws->nc[b];
        out[0] = (float)(sred[0] / (denom + 1e-8));
    }
}

extern "C" void kernel_launch(void* const* d_in, const int* in_sizes, int n_in,
                              void* d_out, int out_size, void* d_ws, size_t ws_size,
                              hipStream_t stream) {
    (void)n_in; (void)out_size; (void)ws_size;
    const int*   ids   = (const int*)d_in[0];
    const void*  tf    = d_in[1];
    const void*  act   = d_in[2];
    const int*   prior = (const int*)d_in[3];
    const int    M     = in_sizes[3];
    const float* u     = (const float*)d_in[4];
    const float* v     = (const float*)d_in[5];
    Ws* ws = (Ws*)d_ws;
    float* out = (float*)d_out;

    prep_kernel<<<PREP_BLOCKS, 1024, 0, stream>>>(ids, tf, act, u, v, ws);
    dim3 grid(16, 16, BB);
    prior_loss_main<<<grid, 256, 0, stream>>>(ws);
    int pbx = (M + 255) / 256;
    if (pbx * BB > PPMAX) pbx = PPMAX / BB;   // safety clamp
    dim3 pgrid(pbx, BB);
    positives_kernel<<<pgrid, 256, 0, stream>>>(prior, M, u, v, ws);
    finalize_kernel<<<1, 256, 0, stream>>>(ws, pbx * BB, out);
}

// Round 10
// 114.995 us; speedup vs baseline: 2.0696x; 1.1001x over previous
//
#include <hip/hip_runtime.h>
#include <math.h>

#define BB 8
#define SS 2048
#define DD 64
#define PAIR_BASE 20000
#define CEPS 1e-8f
#define NROWS (BB * SS)
#define MAIN_BLOCKS (16 * 16 * BB)     // worst-case GEMM grid (early-exit)
#define PPMAX 1024                     // max positives blocks (M <= 262144)
// prep: 64 compact (8 batch x 8 slice) + 8 row-chain + 8 col-chain + 1 detect
#define PREP_BLOCKS (64 + BB + BB + 1)

typedef __bf16 bf16x8 __attribute__((ext_vector_type(8)));
typedef __bf16 bf16x4 __attribute__((ext_vector_type(4)));
typedef float  f32x4  __attribute__((ext_vector_type(4)));

// Workspace (~5.6 MB): per-block partials only; no cross-block atomics/fences
// on the hot path (R7 lesson: 6k same-address device atomics = 155 us).
struct Ws {
    int byteMode;
    int pad;
    int mc[BB];                       // compacted TF-row count per batch
    int nc[BB];                       // compacted active-col count per batch
    float mpart[MAIN_BLOCKS];
    float ppart[PPMAX];
    int cheadR[BB * PAIR_BASE];       // id -> first TF row s (mask-filtered)
    int cnextR[NROWS];
    int cheadC[BB * PAIR_BASE];       // id -> first active col t
    int cnextC[NROWS];
    __bf16 Uc[(size_t)BB * SS * DD];  // compacted TF rows of u (bf16, zero-pad)
    __bf16 Vc[(size_t)BB * SS * DD];  // compacted active rows of v
};

__device__ __forceinline__ bool read_mask(const void* p, int i, int byteMode) {
    if (byteMode) return ((const unsigned char*)p)[i] != 0;
    return ((const int*)p)[i] != 0;
}

// Mask-dtype detect from first 4 KB of tf (valid in both layouts; byte-mode
// false-negative prob 8^-1024).  Requires 1024 threads.
__device__ __forceinline__ int detect_bm(const void* tf_raw, int tid, int* badl) {
    if (tid == 0) *badl = 0;
    __syncthreads();
    if (((const unsigned int*)tf_raw)[tid] > 1u) atomicOr(badl, 1);
    __syncthreads();
    return *badl;
}

// Kernel 0 (prep; 81 blocks x 1024):
//   blocks 0..63  : compaction, (batch b = blk>>3, slice = blk&7).  Each block
//                   redundantly recomputes the cheap ballot scan, then gathers
//                   its 256-compacted-row slice of Uc/Vc (64-CU parallelism).
//   blocks 64..71 : per-batch TF-row chains (id -> rows)
//   blocks 72..79 : per-batch active-col chains (id -> cols)
//   block  80     : publish byteMode
__global__ __launch_bounds__(1024) void prep_kernel(
    const int* __restrict__ ids,
    const void* __restrict__ tf_raw,
    const void* __restrict__ act_raw,
    const float* __restrict__ u,
    const float* __restrict__ v,
    Ws* __restrict__ ws)
{
    __shared__ int badl;
    __shared__ int wsum[16], wbase[16], stot;
    __shared__ unsigned short cidx[SS];

    const int blk  = blockIdx.x;
    const int tid  = threadIdx.x;
    const int w    = tid >> 6;
    const int lane = tid & 63;

    if (blk < 64) {
        // ---- sliced compaction ----
        const int b     = blk >> 3;
        const int slice = blk & 7;
        const int bm = detect_bm(tf_raw, tid, &badl);
        const unsigned long long below = ((unsigned long long)1 << lane) - 1;

        for (int phase = 0; phase < 2; ++phase) {
            const void* mraw = phase ? act_raw : tf_raw;
            const int e0 = b * SS + 2 * tid;
            const int m0 = read_mask(mraw, e0,     bm) ? 1 : 0;
            const int m1 = read_mask(mraw, e0 + 1, bm) ? 1 : 0;
            const unsigned long long k0 = __ballot(m0 != 0);
            const unsigned long long k1 = __ballot(m1 != 0);
            const int exclw = __popcll(k0 & below) + __popcll(k1 & below);
            if (lane == 0) wsum[w] = __popcll(k0) + __popcll(k1);
            __syncthreads();
            if (tid == 0) {
                int run = 0;
                #pragma unroll
                for (int k = 0; k < 16; ++k) { wbase[k] = run; run += wsum[k]; }
                stot = run;
            }
            __syncthreads();
            const int excl = wbase[w] + exclw;
            if (m0) cidx[excl]      = (unsigned short)(2 * tid);
            if (m1) cidx[excl + m0] = (unsigned short)(2 * tid + 1);
            __syncthreads();
            const int total = stot;
            if (tid == 0 && slice == 0) {
                if (phase) ws->nc[b] = total; else ws->mc[b] = total;
            }
            const int tpad = (total + 127) & ~127;
            const int rbeg = slice * 256;
            const int rend = min(rbeg + 256, tpad);
            __bf16* dst = (phase ? ws->Vc : ws->Uc) + (size_t)b * SS * DD;
            const float* src = (phase ? v : u) + (size_t)b * SS * DD;
            const int r_off = tid >> 4, c = tid & 15;   // 16 threads/row, 64 rows/pass
            #pragma unroll
            for (int p4 = 0; p4 < 4; ++p4) {
                const int r = rbeg + p4 * 64 + r_off;
                if (r < rend) {
                    bf16x4 hv;
                    if (r < total) {
                        const float4 f = *(const float4*)(src + (size_t)cidx[r] * DD + c * 4);
                        hv = (bf16x4){ (__bf16)f.x, (__bf16)f.y, (__bf16)f.z, (__bf16)f.w };
                    } else {
                        hv = (bf16x4){ (__bf16)0.f, (__bf16)0.f, (__bf16)0.f, (__bf16)0.f };
                    }
                    *(bf16x4*)(dst + (size_t)r * DD + c * 4) = hv;
                }
            }
            __syncthreads();   // before next phase reuses cidx/wsum
        }
    } else if (blk < 64 + BB) {
        // ---- TF-row chains ----
        const int b = blk - 64;
        const int bm = detect_bm(tf_raw, tid, &badl);
        int* head = ws->cheadR + b * PAIR_BASE;
        for (int i = tid; i < PAIR_BASE; i += 1024) head[i] = -1;
        __syncthreads();
        for (int s = tid; s < SS; s += 1024) {
            if (read_mask(tf_raw, b * SS + s, bm)) {
                const int id = ids[b * SS + s];
                const int old = atomicExch(&head[id], s);
                ws->cnextR[b * SS + s] = old;
            }
        }
    } else if (blk < 64 + 2 * BB) {
        // ---- active-col chains ----
        const int b = blk - (64 + BB);
        const int bm = detect_bm(tf_raw, tid, &badl);
        int* head = ws->cheadC + b * PAIR_BASE;
        for (int i = tid; i < PAIR_BASE; i += 1024) head[i] = -1;
        __syncthreads();
        for (int t = tid; t < SS; t += 1024) {
            if (read_mask(act_raw, b * SS + t, bm)) {
                const int id = ids[b * SS + t];
                const int old = atomicExch(&head[id], t);
                ws->cnextC[b * SS + t] = old;
            }
        }
    } else {
        const int bm = detect_bm(tf_raw, tid, &badl);
        if (tid == 0) ws->byteMode = bm;
    }
}

// Kernel 1 (work): GEMM tiles + prior-entry-driven positives in one launch.
//   blocks [0, MAIN_BLOCKS)      : compacted MFMA tile -> mpart
//   blocks [MAIN_BLOCKS, +npos)  : 256 prior entries each, 8-batch loop -> ppart
// Plain partial stores only; kernel boundary orders them for finalize.
__global__ __launch_bounds__(256) void work_kernel(
    const int* __restrict__ prior, int M,
    const float* __restrict__ u,
    const float* __restrict__ v,
    Ws* __restrict__ ws)
{
    __shared__ __align__(16) __bf16 Ulds[128 * 72];
    __shared__ __align__(16) __bf16 Vlds[128 * 72];
    __shared__ float wsumS[4];

    const int bid  = blockIdx.x;
    const int tid  = threadIdx.x;
    const int w    = tid >> 6;
    const int lane = tid & 63;

    float lsum = 0.f;
    float* slot;

    if (bid < MAIN_BLOCKS) {
        // ================= GEMM tile =================
        const int b  = bid >> 8;
        const int by = (bid >> 4) & 15;
        const int bx = bid & 15;
        const int s0 = by * 128;
        const int t0 = bx * 128;
        slot = &ws->mpart[bid];

        const int mcp = (ws->mc[b] + 127) & ~127;
        const int ncp = (ws->nc[b] + 127) & ~127;
        if (s0 < mcp && t0 < ncp) {
            const __bf16* ub = ws->Uc + (size_t)(b * SS + s0) * DD;
            const __bf16* vb = ws->Vc + (size_t)(b * SS + t0) * DD;
            #pragma unroll
            for (int it = 0; it < 4; ++it) {
                int li = tid + it * 256;      // 128 rows x 8 chunks of 8 bf16
                int r  = li >> 3;
                int c8 = li & 7;
                *(bf16x8*)&Ulds[r * 72 + c8 * 8] = *(const bf16x8*)(ub + r * DD + c8 * 8);
                *(bf16x8*)&Vlds[r * 72 + c8 * 8] = *(const bf16x8*)(vb + r * DD + c8 * 8);
            }
            __syncthreads();

            const int quad = lane >> 4;
            const int l15  = lane & 15;
            const int wm0  = (w >> 1) * 64;
            const int wn0  = (w & 1) * 64;

            f32x4 acc[4][4];
            #pragma unroll
            for (int i = 0; i < 4; ++i)
                #pragma unroll
                for (int j = 0; j < 4; ++j)
                    acc[i][j] = (f32x4){0.f, 0.f, 0.f, 0.f};

            #pragma unroll
            for (int kh = 0; kh < 2; ++kh) {
                const int kcol = kh * 32 + quad * 8;
                bf16x8 af[4], bfr[4];
                #pragma unroll
                for (int ti = 0; ti < 4; ++ti)
                    af[ti] = *(const bf16x8*)&Ulds[(wm0 + ti * 16 + l15) * 72 + kcol];
                #pragma unroll
                for (int tj = 0; tj < 4; ++tj)
                    bfr[tj] = *(const bf16x8*)&Vlds[(wn0 + tj * 16 + l15) * 72 + kcol];
                #pragma unroll
                for (int ti = 0; ti < 4; ++ti)
                    #pragma unroll
                    for (int tj = 0; tj < 4; ++tj)
                        acc[ti][tj] = __builtin_amdgcn_mfma_f32_16x16x32_bf16(
                            af[ti], bfr[tj], acc[ti][tj], 0, 0, 0);
            }

            // Pad rows/cols: dot=0 -> q=1 -> log=0.  Mask-free epilogue.
            // C/D layout: col = lane&15, row = quad*4 + reg.
            #pragma unroll
            for (int ti = 0; ti < 4; ++ti)
                #pragma unroll
                for (int r = 0; r < 4; ++r)
                    #pragma unroll
                    for (int tj = 0; tj < 4; ++tj) {
                        float q = 1.0f - acc[ti][tj][r];
                        q = fminf(fmaxf(q, CEPS), 1.0f - CEPS);
                        lsum += __logf(q);
                    }
            lsum = -lsum;
        }
    } else {
        // ============ positives: 1 lane per prior entry, 8-batch loop ============
        const int pid = bid - MAIN_BLOCKS;
        const int i   = pid * 256 + tid;
        slot = &ws->ppart[pid];

        if (i < M) {
            const int key = prior[i];
            const bool dup = (i > 0) && (prior[i - 1] == key);   // isin dedupe
            if (!dup) {
                const unsigned int uk  = (unsigned int)key;
                const unsigned int src = uk / PAIR_BASE;          // magic-mul
                const unsigned int tgt = uk - src * PAIR_BASE;
                #pragma unroll
                for (int b = 0; b < BB; ++b) {
                    int r = ws->cheadR[b * PAIR_BASE + (int)src];
                    if (r < 0) continue;                          // ~95% of lanes
                    const int thead = ws->cheadC[b * PAIR_BASE + (int)tgt];
                    if (thead < 0) continue;
                    const int* nxtR = ws->cnextR + b * SS;
                    const int* nxtC = ws->cnextC + b * SS;
                    for (; r >= 0; r = nxtR[r]) {
                        const float* urow = u + (size_t)(b * SS + r) * DD;
                        for (int t = thead; t >= 0; t = nxtC[t]) {
                            const float* vrow = v + (size_t)(b * SS + t) * DD;
                            float dot = 0.f;
                            #pragma unroll
                            for (int k2 = 0; k2 < DD; k2 += 4) {
                                float4 a = *(const float4*)(urow + k2);
                                float4 c = *(const float4*)(vrow + k2);
                                dot += (float)(__bf16)a.x * (float)(__bf16)c.x;
                                dot += (float)(__bf16)a.y * (float)(__bf16)c.y;
                                dot += (float)(__bf16)a.z * (float)(__bf16)c.z;
                                dot += (float)(__bf16)a.w * (float)(__bf16)c.w;
                            }
                            float p = fminf(fmaxf(dot, CEPS), 1.0f - CEPS);
                            float q = fminf(fmaxf(1.0f - dot, CEPS), 1.0f - CEPS);
                            lsum += __logf(q) - __logf(p);
                        }
                    }
                }
            }
        }
    }

    // ---- tail: block-reduce partial, plain store ----
    #pragma unroll
    for (int o = 32; o > 0; o >>= 1)
        lsum += __shfl_down(lsum, o, 64);
    if (lane == 0) wsumS[w] = lsum;
    __syncthreads();
    if (tid == 0)
        *slot = wsumS[0] + wsumS[1] + wsumS[2] + wsumS[3];
}

// Kernel 2: finalize — double-sum partials + closed-form denominator.
__global__ __launch_bounds__(256) void finalize_kernel(const Ws* __restrict__ ws,
                                                       int npp,
                                                       float* __restrict__ out) {
    __shared__ double sred[256];
    const int tid = threadIdx.x;
    double s = 0.0;
    for (int i = tid; i < MAIN_BLOCKS; i += 256) s += (double)ws->mpart[i];
    for (int i = tid; i < npp;         i += 256) s += (double)ws->ppart[i];
    sred[tid] = s;
    __syncthreads();
    for (int o = 128; o > 0; o >>= 1) {
        if (tid < o) sred[tid] += sred[tid + o];
        __syncthreads();
    }
    if (tid == 0) {
        double denom = 0.0;
        for (int b = 0; b < BB; ++b)
            denom += (double)ws->mc[b] * (double)ws->nc[b];
        out[0] = (float)(sred[0] / (denom + 1e-8));
    }
}

extern "C" void kernel_launch(void* const* d_in, const int* in_sizes, int n_in,
                              void* d_out, int out_size, void* d_ws, size_t ws_size,
                              hipStream_t stream) {
    (void)n_in; (void)out_size; (void)ws_size;
    const int*   ids   = (const int*)d_in[0];
    const void*  tf    = d_in[1];
    const void*  act   = d_in[2];
    const int*   prior = (const int*)d_in[3];
    const int    M     = in_sizes[3];
    const float* u     = (const float*)d_in[4];
    const float* v     = (const float*)d_in[5];
    Ws* ws = (Ws*)d_ws;
    float* out = (float*)d_out;

    int npos = (M + 255) / 256;
    if (npos > PPMAX) npos = PPMAX;

    prep_kernel<<<PREP_BLOCKS, 1024, 0, stream>>>(ids, tf, act, u, v, ws);
    work_kernel<<<MAIN_BLOCKS + npos, 256, 0, stream>>>(prior, M, u, v, ws);
    finalize_kernel<<<1, 256, 0, stream>>>(ws, npos, out);
}